// Round 3
// baseline (89.435 us; speedup 1.0000x reference)
//
#include <hip/hip_runtime.h>

#ifndef __has_builtin
#define __has_builtin(x) 0
#endif

__device__ __forceinline__ float fexp2(float v) {
#if __has_builtin(__builtin_amdgcn_exp2f)
    return __builtin_amdgcn_exp2f(v);   // raw v_exp_f32
#else
    return exp2f(v);
#endif
}
__device__ __forceinline__ float frcp(float v) {
#if __has_builtin(__builtin_amdgcn_rcpf)
    return __builtin_amdgcn_rcpf(v);    // raw v_rcp_f32 (~1 ulp; threshold 1.5e-2)
#else
    return 1.0f / v;
#endif
}

// Problem constants: B, CIN, H, W = 8, 1, 192, 192; COUT, KH, KW = 8, 7, 7
constexpr int B_    = 8;
constexpr int H_    = 192;
constexpr int W_    = 192;
constexpr int COUT_ = 8;
constexpr int KH_   = 7;
constexpr int KW_   = 7;
constexpr int HO_   = H_ - KH_ + 1;  // 186
constexpr int WO_   = W_ - KW_ + 1;  // 186
constexpr float LOG2E = 1.44269504088896340736f;

constexpr int TX   = 64;             // output tile x per block
constexpr int TY   = 32;             // output tile y per block
constexpr int IX   = TX + KW_ - 1;   // 70 input cols staged
constexpr int IY   = TY + KH_ - 1;   // 38 input rows staged
constexpr int NPIX = IX * IY;        // 2660
constexpr int NSLOT = (NPIX + 255) / 256;  // 11 staging slots/thread

// ws table: per (c,ky) one 16-float row: [F0..F6, 0, G0..G6, 0]
// F = exp(a*f) (as exp2 of a*log2e*f), G = F*f. One s_load_dwordx16 per row.
__global__ void smorph_setup(const float* __restrict__ filt,
                             const float* __restrict__ alpha,
                             float* __restrict__ ws) {
    int i = threadIdx.x;                 // 64 threads, 56 active
    if (i < COUT_ * KH_) {
        int c = i / 7, ky = i - c * 7;
        float a2 = alpha[c] * LOG2E;
        float* t = ws + (c * 7 + ky) * 16;
#pragma unroll
        for (int kx = 0; kx < 7; ++kx) {
            float f = filt[(c * 7 + ky) * 7 + kx];
            float F = fexp2(a2 * f);
            t[kx]     = F;
            t[8 + kx] = F * f;
        }
        t[7] = 0.f; t[15] = 0.f;
    }
}

// exp(a(x+f)) = P * F_k with P = exp2(a2*x).  H = x*P.
// num = sum_k (F_k*H + G_k*P); den = sum_k F_k*P; out = num/den.
//
// 8 outputs/thread (2x * 4y), tile 64x32.
// LDS bytes/output: 224 -> 80 (each staged row read once serves 4 output
// rows); 16 independent acc chains (was 4) for ILP; staged-exp count
// drops 4.5M -> 3.06M. LDS 21.3 KB/block, grid (3,6,64)=1152 blocks.
__global__ __launch_bounds__(256) void smorph_main(
    const float* __restrict__ x,      // (B,1,H,W)
    const float* __restrict__ alpha,  // (COUT,1)
    const float* __restrict__ fg,     // setup table
    float* __restrict__ out)          // (B,COUT,HO,WO)
{
    __shared__ __align__(16) float2 PH[IY * IX];   // 21280 B

    const int tx  = threadIdx.x;      // 0..31
    const int ty  = threadIdx.y;      // 0..7
    const int tid = ty * 32 + tx;
    const int bx0 = blockIdx.x * TX;
    const int by0 = blockIdx.y * TY;
    const int z   = blockIdx.z;       // b*COUT + c
    const int c   = z & 7;
    const float* xb = x + (z >> 3) * (H_ * W_);
    const float a2  = alpha[c] * LOG2E;   // uniform -> s_load

    // Phase 1: stage P,H. 11 slots/thread (last slot: 100 threads active).
#pragma unroll
    for (int s = 0; s < NSLOT; ++s) {
        const int i = tid + 256 * s;
        if (i < NPIX) {
            const int iy = i / IX, ix = i - iy * IX;
            // Clamped coords only feed rows/cols >= H/W which only reach
            // outputs >= HO/WO (masked at store).
            const float xv = xb[min(by0 + iy, H_ - 1) * W_ + min(bx0 + ix, W_ - 1)];
            const float P = fexp2(a2 * xv);
            PH[i] = make_float2(P, xv * P);
        }
    }
    __syncthreads();   // the only barrier in the kernel

    // Phase 2: 7x7 correlation, 8 outputs/thread (2 in x, 4 in y).
    const int ox  = bx0 + 2 * tx;
    const int oyb = by0 + 4 * ty;
    const bool vx = (ox + 1 < WO_);   // ox even: both-or-neither in x

    float num[4][2] = {};
    float den[4][2] = {};
    const float* tc = fg + c * (7 * 16);

    // Each staged input row ir (of 10) is read ONCE and feeds every output
    // row ro with 0 <= ir - ro <= 6. F/G come from scalar cache (uniform).
#pragma unroll
    for (int ir = 0; ir < 4 + KH_ - 1; ++ir) {        // 10 input rows
        const float4* rp = (const float4*)&PH[(4 * ty + ir) * IX + 2 * tx];
        float4 q0 = rp[0], q1 = rp[1], q2 = rp[2], q3 = rp[3];
        float P[8]  = {q0.x, q0.z, q1.x, q1.z, q2.x, q2.z, q3.x, q3.z};
        float Hh[8] = {q0.y, q0.w, q1.y, q1.w, q2.y, q2.w, q3.y, q3.w};
#pragma unroll
        for (int ro = 0; ro < 4; ++ro) {
            const int ky = ir - ro;
            if (ky < 0 || ky > KH_ - 1) continue;
            const float* t = tc + ky * 16;   // uniform -> s_load_dwordx16
#pragma unroll
            for (int kx = 0; kx < 7; ++kx) {
                const float F = t[kx], G = t[8 + kx];
                num[ro][0] = fmaf(F, Hh[kx],     num[ro][0]);
                num[ro][0] = fmaf(G, P[kx],      num[ro][0]);
                den[ro][0] = fmaf(F, P[kx],      den[ro][0]);
                num[ro][1] = fmaf(F, Hh[kx + 1], num[ro][1]);
                num[ro][1] = fmaf(G, P[kx + 1],  num[ro][1]);
                den[ro][1] = fmaf(F, P[kx + 1],  den[ro][1]);
            }
        }
    }

#pragma unroll
    for (int ro = 0; ro < 4; ++ro) {
        const int oy = oyb + ro;
        if (vx && oy < HO_) {
            float2 o;
            o.x = num[ro][0] * frcp(den[ro][0]);
            o.y = num[ro][1] * frcp(den[ro][1]);
            *(float2*)&out[(z * HO_ + oy) * WO_ + ox] = o;
        }
    }
}

extern "C" void kernel_launch(void* const* d_in, const int* in_sizes, int n_in,
                              void* d_out, int out_size, void* d_ws, size_t ws_size,
                              hipStream_t stream) {
    const float* x     = (const float*)d_in[0];
    const float* filt  = (const float*)d_in[1];
    const float* alpha = (const float*)d_in[2];
    float* out = (float*)d_out;
    float* ws  = (float*)d_ws;

    smorph_setup<<<1, 64, 0, stream>>>(filt, alpha, ws);

    dim3 block(32, 8, 1);
    dim3 grid((WO_ + TX - 1) / TX, (HO_ + TY - 1) / TY, B_ * COUT_);  // (3, 6, 64)
    smorph_main<<<grid, block, 0, stream>>>(x, alpha, ws, out);
}